// Round 2
// baseline (57809.991 us; speedup 1.0000x reference)
//
#include <hip/hip_runtime.h>
#include <math.h>
#include <stdint.h>
#include <limits.h>

#define VSZ 50257
#define ESZ 256
#define HSZ 1024
#define BSZ 64
#define TSZ 80
#define GC  4096            // 4*H gate columns
#define NVB 393             // ceil(VSZ/128)
#define NCAND (NVB*5)       // 1965 candidates per batch row

typedef unsigned int u32;

// ---------------- Threefry-2x32 (JAX exact) ----------------
__device__ __forceinline__ void tf2x32(u32 k0, u32 k1, u32& x0, u32& x1) {
  u32 ks2 = k0 ^ k1 ^ 0x1BD11BDAu;
  x0 += k0; x1 += k1;
#define RND(r) { x0 += x1; x1 = (x1 << r) | (x1 >> (32 - r)); x1 ^= x0; }
  RND(13) RND(15) RND(26) RND(6)
  x0 += k1; x1 += ks2 + 1u;
  RND(17) RND(29) RND(16) RND(24)
  x0 += ks2; x1 += k0 + 2u;
  RND(13) RND(15) RND(26) RND(6)
  x0 += k0; x1 += k1 + 3u;
  RND(17) RND(29) RND(16) RND(24)
  x0 += k1; x1 += ks2 + 4u;
  RND(13) RND(15) RND(26) RND(6)
  x0 += ks2; x1 += k0 + 5u;
#undef RND
}

__device__ __forceinline__ double dsig(double x) { return 0.5 + 0.5 * tanh(0.5 * x); }

// sorted-desc top5 insert; ties -> lower index first (matches lax.top_k)
__device__ __forceinline__ void ins5(double v, int i, double* tv, int* ti) {
  bool beat4 = (v > tv[4]) || (v == tv[4] && i < ti[4]);
  if (!beat4) return;
  tv[4] = v; ti[4] = i;
#pragma unroll
  for (int p = 4; p > 0; --p) {
    bool sw = (tv[p] > tv[p-1]) || (tv[p] == tv[p-1] && ti[p] < ti[p-1]);
    double a0 = sw ? tv[p] : tv[p-1]; double a1 = sw ? tv[p-1] : tv[p];
    tv[p-1] = a0; tv[p] = a1;
    int b0 = sw ? ti[p] : ti[p-1]; int b1 = sw ? ti[p-1] : ti[p];
    ti[p-1] = b0; ti[p] = b1;
  }
}

// -------- fused RNG: gumbel[t][m] for t<80, m<320 --------
__global__ __launch_bounds__(256) void k_rng(double* __restrict__ gum) {
  int idx = blockIdx.x * 256 + threadIdx.x;
  if (idx >= TSZ * 320) return;
  int t = idx / 320, m = idx % 320;
  u32 a0 = 0u, a1 = (u32)t;
  tf2x32(0u, 42u, a0, a1);            // keys[t] = split(key(42))[t]
  u32 x0 = 0u, x1 = (u32)m;
  tf2x32(a0, a1, x0, x1);             // random_bits(key_t)[m]
  u32 bits = x0 ^ x1;
  const float TINY = 1.17549435082228750797e-38f;  // 2^-126
  float f = __uint_as_float((bits >> 9) | 0x3f800000u) - 1.0f;
  float u = f + TINY;
  u = fmaxf(TINY, u);
  gum[idx] = -log(-log((double)u));
}

// -------- time encode stage 1 --------
__global__ __launch_bounds__(256) void k_time1(const float* __restrict__ hours, const float* __restrict__ w1,
                                               const float* __restrict__ bb1, double* __restrict__ tp1T) {
  int idx = blockIdx.x * 256 + threadIdx.x;  // 64*1024
  int b = idx & 63, hcol = idx >> 6;
  const float TPO = (float)(2.0 * 3.14159265358979323846 / 24.0);
  float af = hours[b] * TPO;
  double a = (double)af;
  double sv = sin(a), cv = cos(a);
  double vv = tanh(sv * (double)w1[hcol] + cv * (double)w1[HSZ + hcol] + (double)bb1[hcol]);
  tp1T[(size_t)hcol * 64 + b] = vv;
}

// -------- simple split-K gemm (prologue-only, perf irrelevant) --------
__global__ __launch_bounds__(256) void k_gemm_simple(const double* __restrict__ XTa, const float* __restrict__ Wa,
                                                     int Ka, int Sa, double* __restrict__ part) {
  int j = blockIdx.x * 256 + threadIdx.x;
  if (j >= GC) return;
  int s = blockIdx.y;
  int kc = Ka / Sa, k0 = s * kc;
  double acc[BSZ];
#pragma unroll
  for (int b = 0; b < BSZ; ++b) acc[b] = 0.0;
  const float* wp = Wa + (size_t)k0 * GC + j;
  const double* xp = XTa + (size_t)k0 * 64;
  for (int k = 0; k < kc; ++k) {
    double wv = (double)wp[0]; wp += GC;
#pragma unroll
    for (int b = 0; b < BSZ; ++b) acc[b] = fma(wv, xp[b], acc[b]);
    xp += 64;
  }
  double* o = part + ((size_t)s * 64) * GC + j;
#pragma unroll
  for (int b = 0; b < BSZ; ++b) o[(size_t)b * GC] = acc[b];
}

// -------- time encode stage 2 reduce --------
__global__ __launch_bounds__(256) void k_t2r(const double* __restrict__ part, const float* __restrict__ b2,
                                             double* __restrict__ h0T, double* __restrict__ c0,
                                             double* __restrict__ h1T, double* __restrict__ c1) {
  int b = blockIdx.y;
  int j = blockIdx.x * 256 + threadIdx.x;
  double acc = (double)b2[j];
  for (int s = 0; s < 8; ++s) acc += part[((size_t)s * 64 + b) * GC + j];
  int l = j >> 11, half = (j >> 10) & 1, hcol = j & 1023;
  if (half == 0) (l ? h1T : h0T)[(size_t)hcol * 64 + b] = acc;
  else           (l ? c1 : c0)[(size_t)b * HSZ + hcol] = acc;
}

// -------- LSTM gemm: LDS-staged x, 4col x 8batch register blocking --------
// thread t: vg = t&31 (col = colbase+vg+32*i), bg = t>>5 (b = bg*8+j)
__global__ __launch_bounds__(256) void k_lstm(const double* __restrict__ XTa, const float* __restrict__ Wa,
                                              int Ka, int Sa,
                                              const double* __restrict__ XTb, const float* __restrict__ Wb,
                                              int Kb, int Sb,
                                              double* __restrict__ part) {
  __shared__ double xs[128 * 64];
  int tid = threadIdx.x;
  int vg = tid & 31, bg = tid >> 5;
  int colbase = blockIdx.x * 128;
  int s = blockIdx.y;
  const double* XT; const float* W; int k0, kc;
  if (s < Sa) { kc = Ka / Sa; XT = XTa; W = Wa; k0 = s * kc; }
  else        { kc = Kb / Sb; XT = XTb; W = Wb; k0 = (s - Sa) * kc; }
  int nch = kc >> 7;
  double acc[4][8];
#pragma unroll
  for (int i = 0; i < 4; ++i)
#pragma unroll
    for (int j = 0; j < 8; ++j) acc[i][j] = 0.0;

  for (int ch = 0; ch < nch; ++ch) {
    __syncthreads();
    const double2* src = (const double2*)(XT + (size_t)(k0 + ch * 128) * 64);
    double2* dst = (double2*)xs;
    for (int i = tid; i < 4096; i += 256) dst[i] = src[i];
    __syncthreads();
    const float* wr = W + (size_t)(k0 + ch * 128) * GC + colbase + vg;
    const double2* xp = (const double2*)(xs + bg * 8);
    for (int k = 0; k < 128; ++k) {
      double w0 = (double)wr[0], w1 = (double)wr[32], w2 = (double)wr[64], w3 = (double)wr[96];
#pragma unroll
      for (int j2 = 0; j2 < 4; ++j2) {
        double2 xx = xp[j2];
        acc[0][2*j2]   = fma(w0, xx.x, acc[0][2*j2]);
        acc[0][2*j2+1] = fma(w0, xx.y, acc[0][2*j2+1]);
        acc[1][2*j2]   = fma(w1, xx.x, acc[1][2*j2]);
        acc[1][2*j2+1] = fma(w1, xx.y, acc[1][2*j2+1]);
        acc[2][2*j2]   = fma(w2, xx.x, acc[2][2*j2]);
        acc[2][2*j2+1] = fma(w2, xx.y, acc[2][2*j2+1]);
        acc[3][2*j2]   = fma(w3, xx.x, acc[3][2*j2]);
        acc[3][2*j2+1] = fma(w3, xx.y, acc[3][2*j2+1]);
      }
      wr += GC; xp += 32;
    }
  }
#pragma unroll
  for (int j = 0; j < 8; ++j) {
    int b = bg * 8 + j;
    double* o = part + ((size_t)s * 64 + b) * GC + colbase + vg;
    o[0]  = acc[0][j];
    o[32] = acc[1][j];
    o[64] = acc[2][j];
    o[96] = acc[3][j];
  }
}

// -------- LSTM cell: sum partials + bias, gate order i,f,g,o --------
__global__ __launch_bounds__(256) void k_cell(const double* __restrict__ part, int S,
                                              const float* __restrict__ bias,
                                              double* __restrict__ c, double* __restrict__ hT) {
  int b = blockIdx.y;
  int hcol = blockIdx.x * 256 + threadIdx.x;
  double gi = (double)bias[hcol];
  double gf = (double)bias[1024 + hcol];
  double gg = (double)bias[2048 + hcol];
  double go = (double)bias[3072 + hcol];
  for (int s = 0; s < S; ++s) {
    const double* p = part + ((size_t)s * 64 + b) * GC;
    gi += p[hcol]; gf += p[1024 + hcol]; gg += p[2048 + hcol]; go += p[3072 + hcol];
  }
  size_t ci = (size_t)b * HSZ + hcol;
  double cn = dsig(gf) * c[ci] + dsig(gi) * tanh(gg);
  double hn = dsig(go) * tanh(cn);
  c[ci] = cn;
  hT[(size_t)hcol * 64 + b] = hn;
}

// -------- fused FC + per-block top5: block = 128 vocab cols, full K=1024 --------
__global__ __launch_bounds__(256) void k_fctop(const double* __restrict__ h1T, const float* __restrict__ W,
                                               const float* __restrict__ fcb,
                                               double* __restrict__ candV, int* __restrict__ candI) {
  __shared__ double smem[64 * 128];   // 64KB: x-staging (8192 dbl) / transpose buffer
  int tid = threadIdx.x;
  int vg = tid & 31, bg = tid >> 5;
  int vbase = blockIdx.x * 128;
  int v0 = vbase + vg;
  int c0 = min(v0,      VSZ - 1);
  int c1 = min(v0 + 32, VSZ - 1);
  int c2 = min(v0 + 64, VSZ - 1);
  int c3 = min(v0 + 96, VSZ - 1);
  double acc[4][8];
#pragma unroll
  for (int i = 0; i < 4; ++i)
#pragma unroll
    for (int j = 0; j < 8; ++j) acc[i][j] = 0.0;

  for (int ch = 0; ch < 8; ++ch) {
    __syncthreads();
    const double2* src = (const double2*)(h1T + (size_t)ch * 128 * 64);
    double2* dst = (double2*)smem;
    for (int i = tid; i < 4096; i += 256) dst[i] = src[i];
    __syncthreads();
    const float* wr = W + (size_t)(ch * 128) * VSZ;
    const double2* xp = (const double2*)(smem + bg * 8);
    for (int k = 0; k < 128; ++k) {
      double w0 = (double)wr[c0], w1 = (double)wr[c1], w2 = (double)wr[c2], w3 = (double)wr[c3];
#pragma unroll
      for (int j2 = 0; j2 < 4; ++j2) {
        double2 xx = xp[j2];
        acc[0][2*j2]   = fma(w0, xx.x, acc[0][2*j2]);
        acc[0][2*j2+1] = fma(w0, xx.y, acc[0][2*j2+1]);
        acc[1][2*j2]   = fma(w1, xx.x, acc[1][2*j2]);
        acc[1][2*j2+1] = fma(w1, xx.y, acc[1][2*j2+1]);
        acc[2][2*j2]   = fma(w2, xx.x, acc[2][2*j2]);
        acc[2][2*j2+1] = fma(w2, xx.y, acc[2][2*j2+1]);
        acc[3][2*j2]   = fma(w3, xx.x, acc[3][2*j2]);
        acc[3][2*j2+1] = fma(w3, xx.y, acc[3][2*j2+1]);
      }
      wr += VSZ; xp += 32;
    }
  }
  __syncthreads();
  // bias + /TEMP, transpose into smem[b][(vl+b)&127] (swizzle kills bank conflicts)
  double bi[4]; bool ok[4];
#pragma unroll
  for (int i = 0; i < 4; ++i) {
    int v = v0 + 32 * i;
    ok[i] = (v < VSZ);
    bi[i] = ok[i] ? (double)fcb[v] : 0.0;
  }
#pragma unroll
  for (int i = 0; i < 4; ++i) {
    int vl = vg + 32 * i;
#pragma unroll
    for (int j = 0; j < 8; ++j) {
      int b = bg * 8 + j;
      double val = ok[i] ? (acc[i][j] + bi[i]) / 0.75 : -INFINITY;
      smem[b * 128 + ((vl + b) & 127)] = val;
    }
  }
  __syncthreads();
  if (tid < 64) {
    int b = tid;
    double tv[5]; int ti[5];
#pragma unroll
    for (int p = 0; p < 5; ++p) { tv[p] = -INFINITY; ti[p] = INT_MAX; }
    for (int vl = 0; vl < 128; ++vl)
      ins5(smem[b * 128 + ((vl + b) & 127)], vbase + vl, tv, ti);
#pragma unroll
    for (int r = 0; r < 5; ++r) {
      candV[((size_t)blockIdx.x * 5 + r) * 64 + b] = tv[r];
      candI[((size_t)blockIdx.x * 5 + r) * 64 + b] = ti[r];
    }
  }
}

// -------- final merge (1965 cands) + gumbel sample + outputs + next embedding --------
__global__ __launch_bounds__(64) void k_fin(const double* __restrict__ candV, const int* __restrict__ candI,
                                            const double* __restrict__ gum, int t,
                                            const float* __restrict__ embed,
                                            float* __restrict__ out, double* __restrict__ xt0) {
  int b = blockIdx.x, lane = threadIdx.x;
  double tv[5]; int ti[5];
#pragma unroll
  for (int p = 0; p < 5; ++p) { tv[p] = -INFINITY; ti[p] = INT_MAX; }
  for (int e = lane; e < NCAND; e += 64)
    ins5(candV[(size_t)e * 64 + b], candI[(size_t)e * 64 + b], tv, ti);
  double mv[5]; int mi[5];
#pragma unroll
  for (int r = 0; r < 5; ++r) {
    double bv = tv[0]; int bi = ti[0];
    for (int off = 1; off < 64; off <<= 1) {
      double ov = __shfl_xor(bv, off, 64);
      int oi = __shfl_xor(bi, off, 64);
      if (ov > bv || (ov == bv && oi < bi)) { bv = ov; bi = oi; }
    }
    mv[r] = bv; mi[r] = bi;
    if (tv[0] == bv && ti[0] == bi) {
#pragma unroll
      for (int p = 0; p < 4; ++p) { tv[p] = tv[p+1]; ti[p] = ti[p+1]; }
      tv[4] = -INFINITY; ti[4] = INT_MAX;
    }
  }
  const double* g = gum + (size_t)t * 320 + b * 5;
  double bestv = mv[0] + g[0]; int best = 0;
#pragma unroll
  for (int k2 = 1; k2 < 5; ++k2) { double vv = mv[k2] + g[k2]; if (vv > bestv) { bestv = vv; best = k2; } }
  int nxt = mi[best];
  if (lane == 0) {
    out[b * TSZ + t] = (float)nxt;
    double m = mv[0];
    double ex[5]; double s = 0.0;
#pragma unroll
    for (int k2 = 0; k2 < 5; ++k2) { ex[k2] = exp(mv[k2] - m); s += ex[k2]; }
    float* po = out + BSZ * TSZ + ((size_t)b * TSZ + t) * 5;
#pragma unroll
    for (int k2 = 0; k2 < 5; ++k2) po[k2] = (float)(ex[k2] / s);
  }
  for (int k = lane; k < ESZ; k += 64)
    xt0[(size_t)k * 64 + b] = (double)embed[(size_t)nxt * ESZ + k];
}

// -------- initial embedding of SOS --------
__global__ __launch_bounds__(256) void k_emb0(const float* __restrict__ embed, const int* __restrict__ sos,
                                              double* __restrict__ xt0) {
  int idx = blockIdx.x * 256 + threadIdx.x;
  int b = idx & 63, k = idx >> 6;
  xt0[(size_t)k * 64 + b] = (double)embed[(size_t)sos[0] * ESZ + k];
}

extern "C" void kernel_launch(void* const* d_in, const int* in_sizes, int n_in,
                              void* d_out, int out_size, void* d_ws, size_t ws_size,
                              hipStream_t stream) {
  const float* hours = (const float*)d_in[0];
  const float* tp_w1 = (const float*)d_in[1];
  const float* tp_b1 = (const float*)d_in[2];
  const float* tp_w2 = (const float*)d_in[3];
  const float* tp_b2 = (const float*)d_in[4];
  const float* embed = (const float*)d_in[5];
  const float* w_ih0 = (const float*)d_in[6];
  const float* w_hh0 = (const float*)d_in[7];
  const float* b0    = (const float*)d_in[8];
  const float* w_ih1 = (const float*)d_in[9];
  const float* w_hh1 = (const float*)d_in[10];
  const float* b1    = (const float*)d_in[11];
  const float* fc_w  = (const float*)d_in[12];
  const float* fc_b  = (const float*)d_in[13];
  const int*   sos   = (const int*)d_in[14];
  float* out = (float*)d_out;

  char* w = (char*)d_ws;
  double* part = (double*)w;  w += (size_t)10 * 64 * GC * 8;      // 20.97 MB split-K partials
  double* xt0  = (double*)w;  w += (size_t)ESZ * 64 * 8;
  double* h0T  = (double*)w;  w += (size_t)HSZ * 64 * 8;
  double* h1T  = (double*)w;  w += (size_t)HSZ * 64 * 8;
  double* c0   = (double*)w;  w += (size_t)BSZ * HSZ * 8;
  double* c1   = (double*)w;  w += (size_t)BSZ * HSZ * 8;
  double* tp1T = (double*)w;  w += (size_t)HSZ * 64 * 8;
  double* gum  = (double*)w;  w += (size_t)TSZ * 320 * 8;
  double* candV = (double*)w; w += (size_t)NCAND * 64 * 8;
  int*    candI = (int*)w;    w += (size_t)NCAND * 64 * 4;

  k_rng<<<dim3(100), dim3(256), 0, stream>>>(gum);
  k_time1<<<dim3(256), dim3(256), 0, stream>>>(hours, tp_w1, tp_b1, tp1T);
  k_gemm_simple<<<dim3(16, 8), dim3(256), 0, stream>>>(tp1T, tp_w2, 1024, 8, part);
  k_t2r<<<dim3(16, 64), dim3(256), 0, stream>>>(part, tp_b2, h0T, c0, h1T, c1);
  k_emb0<<<dim3(64), dim3(256), 0, stream>>>(embed, sos, xt0);

  for (int t = 0; t < TSZ; ++t) {
    k_lstm<<<dim3(32, 10), dim3(256), 0, stream>>>(xt0, w_ih0, 256, 2, h0T, w_hh0, 1024, 8, part);
    k_cell<<<dim3(4, 64), dim3(256), 0, stream>>>(part, 10, b0, c0, h0T);
    k_lstm<<<dim3(32, 8), dim3(256), 0, stream>>>(h0T, w_ih1, 1024, 4, h1T, w_hh1, 1024, 4, part);
    k_cell<<<dim3(4, 64), dim3(256), 0, stream>>>(part, 8, b1, c1, h1T);
    k_fctop<<<dim3(NVB), dim3(256), 0, stream>>>(h1T, fc_w, fc_b, candV, candI);
    k_fin<<<dim3(64), dim3(64), 0, stream>>>(candV, candI, gum, t, embed, out, xt0);
  }
}

// Round 3
// 44590.399 us; speedup vs baseline: 1.2965x; 1.2965x over previous
//
#include <hip/hip_runtime.h>
#include <math.h>
#include <stdint.h>
#include <limits.h>

#define VSZ 50257
#define ESZ 256
#define HSZ 1024
#define BSZ 64
#define TSZ 80
#define GC  4096            // 4*H gate columns
#define NFCB 786            // ceil(VSZ/64) FC col-blocks
#define NCAND (NFCB*5)      // 3930 candidates per batch row
#define NSLOT 26            // part slots: A uses 0..17, B uses 18..25

typedef unsigned int u32;

// ---------------- Threefry-2x32 (JAX exact) ----------------
__device__ __forceinline__ void tf2x32(u32 k0, u32 k1, u32& x0, u32& x1) {
  u32 ks2 = k0 ^ k1 ^ 0x1BD11BDAu;
  x0 += k0; x1 += k1;
#define RND(r) { x0 += x1; x1 = (x1 << r) | (x1 >> (32 - r)); x1 ^= x0; }
  RND(13) RND(15) RND(26) RND(6)
  x0 += k1; x1 += ks2 + 1u;
  RND(17) RND(29) RND(16) RND(24)
  x0 += ks2; x1 += k0 + 2u;
  RND(13) RND(15) RND(26) RND(6)
  x0 += k0; x1 += k1 + 3u;
  RND(17) RND(29) RND(16) RND(24)
  x0 += k1; x1 += ks2 + 4u;
  RND(13) RND(15) RND(26) RND(6)
  x0 += ks2; x1 += k0 + 5u;
#undef RND
}

__device__ __forceinline__ double dsig(double x) { return 0.5 + 0.5 * tanh(0.5 * x); }

// sorted-desc top5 insert; ties -> lower index first (matches lax.top_k)
__device__ __forceinline__ void ins5(double v, int i, double* tv, int* ti) {
  bool beat4 = (v > tv[4]) || (v == tv[4] && i < ti[4]);
  if (!beat4) return;
  tv[4] = v; ti[4] = i;
#pragma unroll
  for (int p = 4; p > 0; --p) {
    bool sw = (tv[p] > tv[p-1]) || (tv[p] == tv[p-1] && ti[p] < ti[p-1]);
    double a0 = sw ? tv[p] : tv[p-1]; double a1 = sw ? tv[p-1] : tv[p];
    tv[p-1] = a0; tv[p] = a1;
    int b0 = sw ? ti[p] : ti[p-1]; int b1 = sw ? ti[p-1] : ti[p];
    ti[p-1] = b0; ti[p] = b1;
  }
}

// -------- fused RNG: gumbel[t][m] for t<80, m<320 --------
__global__ __launch_bounds__(256) void k_rng(double* __restrict__ gum) {
  int idx = blockIdx.x * 256 + threadIdx.x;
  if (idx >= TSZ * 320) return;
  int t = idx / 320, m = idx % 320;
  u32 a0 = 0u, a1 = (u32)t;
  tf2x32(0u, 42u, a0, a1);
  u32 x0 = 0u, x1 = (u32)m;
  tf2x32(a0, a1, x0, x1);
  u32 bits = x0 ^ x1;
  const float TINY = 1.17549435082228750797e-38f;  // 2^-126
  float f = __uint_as_float((bits >> 9) | 0x3f800000u) - 1.0f;
  float u = f + TINY;
  u = fmaxf(TINY, u);
  gum[idx] = -log(-log((double)u));
}

// -------- time encode stage 1 --------
__global__ __launch_bounds__(256) void k_time1(const float* __restrict__ hours, const float* __restrict__ w1,
                                               const float* __restrict__ bb1, double* __restrict__ tp1T) {
  int idx = blockIdx.x * 256 + threadIdx.x;  // 64*1024
  int b = idx & 63, hcol = idx >> 6;
  const float TPO = (float)(2.0 * 3.14159265358979323846 / 24.0);
  float af = hours[b] * TPO;
  double a = (double)af;
  double sv = sin(a), cv = cos(a);
  double vv = tanh(sv * (double)w1[hcol] + cv * (double)w1[HSZ + hcol] + (double)bb1[hcol]);
  tp1T[(size_t)hcol * 64 + b] = vv;
}

// -------- simple split-K gemm (prologue-only, runs once) --------
__global__ __launch_bounds__(256) void k_gemm_simple(const double* __restrict__ XTa, const float* __restrict__ Wa,
                                                     int Ka, int Sa, double* __restrict__ part) {
  int j = blockIdx.x * 256 + threadIdx.x;
  if (j >= GC) return;
  int s = blockIdx.y;
  int kc = Ka / Sa, k0 = s * kc;
  double acc[BSZ];
#pragma unroll
  for (int b = 0; b < BSZ; ++b) acc[b] = 0.0;
  const float* wp = Wa + (size_t)k0 * GC + j;
  const double* xp = XTa + (size_t)k0 * 64;
  for (int k = 0; k < kc; ++k) {
    double wv = (double)wp[0]; wp += GC;
#pragma unroll
    for (int b = 0; b < BSZ; ++b) acc[b] = fma(wv, xp[b], acc[b]);
    xp += 64;
  }
  double* o = part + ((size_t)s * 64) * GC + j;
#pragma unroll
  for (int b = 0; b < BSZ; ++b) o[(size_t)b * GC] = acc[b];
}

// -------- time encode stage 2 reduce --------
__global__ __launch_bounds__(256) void k_t2r(const double* __restrict__ part, const float* __restrict__ b2,
                                             double* __restrict__ h0T, double* __restrict__ c0,
                                             double* __restrict__ h1T, double* __restrict__ c1) {
  int b = blockIdx.y;
  int j = blockIdx.x * 256 + threadIdx.x;
  double acc = (double)b2[j];
  for (int s = 0; s < 8; ++s) acc += part[((size_t)s * 64 + b) * GC + j];
  int l = j >> 11, half = (j >> 10) & 1, hcol = j & 1023;
  if (half == 0) (l ? h1T : h0T)[(size_t)hcol * 64 + b] = acc;
  else           (l ? c1 : c0)[(size_t)b * HSZ + hcol] = acc;
}

// -------- LSTM gemm: 64-col blocks, 32KB LDS chunks, prefetched weights --------
// grid (64, S). slice s: s<s1 -> (x0,W0,k0=s*128); s<s2 -> (x1,W1,(s-s1)*128); else (x2,W2,(s-s2)*128)
// part slot = slotBase + s. kc=128 always (2 chunks of 64).
__global__ __launch_bounds__(256, 4) void k_lstm(const double* __restrict__ x0, const float* __restrict__ W0,
                                                 const double* __restrict__ x1, const float* __restrict__ W1,
                                                 const double* __restrict__ x2, const float* __restrict__ W2,
                                                 int s1, int s2, double* __restrict__ part) {
  __shared__ double xs[64 * 64];   // 32KB
  int tid = threadIdx.x;
  int vg = tid & 31, bg = tid >> 5;
  int colbase = blockIdx.x * 64;
  int s = blockIdx.y;
  const double* XT; const float* W; int k0;
  if (s < s1)      { XT = x0; W = W0; k0 = s * 128; }
  else if (s < s2) { XT = x1; W = W1; k0 = (s - s1) * 128; }
  else             { XT = x2; W = W2; k0 = (s - s2) * 128; }
  double acc[2][8];
#pragma unroll
  for (int i = 0; i < 2; ++i)
#pragma unroll
    for (int j = 0; j < 8; ++j) acc[i][j] = 0.0;

  for (int ch = 0; ch < 2; ++ch) {
    __syncthreads();
    const double2* src = (const double2*)(XT + (size_t)(k0 + ch * 64) * 64);
    double2* dst = (double2*)xs;
    for (int i = tid; i < 2048; i += 256) dst[i] = src[i];
    __syncthreads();
    const float* wr = W + (size_t)(k0 + ch * 64) * GC + colbase + vg;
    float wn0 = wr[0], wn1 = wr[32];
    for (int k = 0; k < 64; ++k) {
      double w0 = (double)wn0, w1 = (double)wn1;
      if (k < 63) { wr += GC; wn0 = wr[0]; wn1 = wr[32]; }
      const double2* xp = (const double2*)xs + (k << 5) + (bg << 2);
      double2 xa = xp[0], xb = xp[1], xc = xp[2], xd = xp[3];
      acc[0][0] = fma(w0, xa.x, acc[0][0]); acc[0][1] = fma(w0, xa.y, acc[0][1]);
      acc[0][2] = fma(w0, xb.x, acc[0][2]); acc[0][3] = fma(w0, xb.y, acc[0][3]);
      acc[0][4] = fma(w0, xc.x, acc[0][4]); acc[0][5] = fma(w0, xc.y, acc[0][5]);
      acc[0][6] = fma(w0, xd.x, acc[0][6]); acc[0][7] = fma(w0, xd.y, acc[0][7]);
      acc[1][0] = fma(w1, xa.x, acc[1][0]); acc[1][1] = fma(w1, xa.y, acc[1][1]);
      acc[1][2] = fma(w1, xb.x, acc[1][2]); acc[1][3] = fma(w1, xb.y, acc[1][3]);
      acc[1][4] = fma(w1, xc.x, acc[1][4]); acc[1][5] = fma(w1, xc.y, acc[1][5]);
      acc[1][6] = fma(w1, xd.x, acc[1][6]); acc[1][7] = fma(w1, xd.y, acc[1][7]);
    }
  }
#pragma unroll
  for (int j = 0; j < 8; ++j) {
    int b = bg * 8 + j;
    double* o = part + ((size_t)s * 64 + b) * GC + colbase + vg;
    o[0]  = acc[0][j];
    o[32] = acc[1][j];
  }
}

// -------- LSTM cell: sum partial slots [sBeg, sBeg+S) + bias; gates i,f,g,o --------
__global__ __launch_bounds__(256) void k_cell(const double* __restrict__ part, int sBeg, int S,
                                              const float* __restrict__ bias,
                                              double* __restrict__ c, double* __restrict__ hT) {
  int b = blockIdx.y;
  int hcol = blockIdx.x * 256 + threadIdx.x;
  double gi = (double)bias[hcol];
  double gf = (double)bias[1024 + hcol];
  double gg = (double)bias[2048 + hcol];
  double go = (double)bias[3072 + hcol];
  for (int s = sBeg; s < sBeg + S; ++s) {
    const double* p = part + ((size_t)s * 64 + b) * GC;
    gi += p[hcol]; gf += p[1024 + hcol]; gg += p[2048 + hcol]; go += p[3072 + hcol];
  }
  size_t ci = (size_t)b * HSZ + hcol;
  double cn = dsig(gf) * c[ci] + dsig(gi) * tanh(gg);
  double hn = dsig(go) * tanh(cn);
  c[ci] = cn;
  hT[(size_t)hcol * 64 + b] = hn;
}

// -------- fused FC + per-block top5: 64 vocab cols/block, full K=1024 --------
__global__ __launch_bounds__(256, 4) void k_fctop(const double* __restrict__ h1T, const float* __restrict__ W,
                                                  const float* __restrict__ fcb,
                                                  double* __restrict__ candV, int* __restrict__ candI) {
  __shared__ double xs[64 * 64];   // 32KB: x-chunk staging, then 64b x 64v transpose buffer
  int tid = threadIdx.x;
  int vg = tid & 31, bg = tid >> 5;
  int vbase = blockIdx.x * 64;
  int c0 = min(vbase + vg,      VSZ - 1);
  int c1 = min(vbase + vg + 32, VSZ - 1);
  double acc[2][8];
#pragma unroll
  for (int i = 0; i < 2; ++i)
#pragma unroll
    for (int j = 0; j < 8; ++j) acc[i][j] = 0.0;

  for (int ch = 0; ch < 16; ++ch) {
    __syncthreads();
    const double2* src = (const double2*)(h1T + (size_t)ch * 64 * 64);
    double2* dst = (double2*)xs;
    for (int i = tid; i < 2048; i += 256) dst[i] = src[i];
    __syncthreads();
    const float* wr = W + (size_t)(ch * 64) * VSZ;
    float wn0 = wr[c0], wn1 = wr[c1];
    for (int k = 0; k < 64; ++k) {
      double w0 = (double)wn0, w1 = (double)wn1;
      if (k < 63) { wr += VSZ; wn0 = wr[c0]; wn1 = wr[c1]; }
      const double2* xp = (const double2*)xs + (k << 5) + (bg << 2);
      double2 xa = xp[0], xb = xp[1], xc = xp[2], xd = xp[3];
      acc[0][0] = fma(w0, xa.x, acc[0][0]); acc[0][1] = fma(w0, xa.y, acc[0][1]);
      acc[0][2] = fma(w0, xb.x, acc[0][2]); acc[0][3] = fma(w0, xb.y, acc[0][3]);
      acc[0][4] = fma(w0, xc.x, acc[0][4]); acc[0][5] = fma(w0, xc.y, acc[0][5]);
      acc[0][6] = fma(w0, xd.x, acc[0][6]); acc[0][7] = fma(w0, xd.y, acc[0][7]);
      acc[1][0] = fma(w1, xa.x, acc[1][0]); acc[1][1] = fma(w1, xa.y, acc[1][1]);
      acc[1][2] = fma(w1, xb.x, acc[1][2]); acc[1][3] = fma(w1, xb.y, acc[1][3]);
      acc[1][4] = fma(w1, xc.x, acc[1][4]); acc[1][5] = fma(w1, xc.y, acc[1][5]);
      acc[1][6] = fma(w1, xd.x, acc[1][6]); acc[1][7] = fma(w1, xd.y, acc[1][7]);
    }
  }
  __syncthreads();
  // bias + /TEMP, transpose into xs[b][(vl+b)&63] (swizzled, conflict-free)
#pragma unroll
  for (int i = 0; i < 2; ++i) {
    int v = vbase + vg + 32 * i;
    bool ok = (v < VSZ);
    double bi = ok ? (double)fcb[v] : 0.0;
    int vl = vg + 32 * i;
#pragma unroll
    for (int j = 0; j < 8; ++j) {
      int b = bg * 8 + j;
      double val = ok ? (acc[i][j] + bi) / 0.75 : -INFINITY;
      xs[b * 64 + ((vl + b) & 63)] = val;
    }
  }
  __syncthreads();
  if (tid < 64) {
    int b = tid;
    double tv[5]; int ti[5];
#pragma unroll
    for (int p = 0; p < 5; ++p) { tv[p] = -INFINITY; ti[p] = INT_MAX; }
    for (int vl = 0; vl < 64; ++vl)
      ins5(xs[b * 64 + ((vl + b) & 63)], vbase + vl, tv, ti);
#pragma unroll
    for (int r = 0; r < 5; ++r) {
      candV[(size_t)b * NCAND + blockIdx.x * 5 + r] = tv[r];
      candI[(size_t)b * NCAND + blockIdx.x * 5 + r] = ti[r];
    }
  }
}

// -------- final merge (3930 cands, b-major/coalesced) + gumbel sample + outputs --------
__global__ __launch_bounds__(64) void k_fin(const double* __restrict__ candV, const int* __restrict__ candI,
                                            const double* __restrict__ gum, int t,
                                            const float* __restrict__ embed,
                                            float* __restrict__ out, double* __restrict__ xt0) {
  int b = blockIdx.x, lane = threadIdx.x;
  double tv[5]; int ti[5];
#pragma unroll
  for (int p = 0; p < 5; ++p) { tv[p] = -INFINITY; ti[p] = INT_MAX; }
  const double* cv = candV + (size_t)b * NCAND;
  const int*    ci = candI + (size_t)b * NCAND;
  for (int e = lane; e < NCAND; e += 64)
    ins5(cv[e], ci[e], tv, ti);
  double mv[5]; int mi[5];
#pragma unroll
  for (int r = 0; r < 5; ++r) {
    double bv = tv[0]; int bi = ti[0];
    for (int off = 1; off < 64; off <<= 1) {
      double ov = __shfl_xor(bv, off, 64);
      int oi = __shfl_xor(bi, off, 64);
      if (ov > bv || (ov == bv && oi < bi)) { bv = ov; bi = oi; }
    }
    mv[r] = bv; mi[r] = bi;
    if (tv[0] == bv && ti[0] == bi) {
#pragma unroll
      for (int p = 0; p < 4; ++p) { tv[p] = tv[p+1]; ti[p] = ti[p+1]; }
      tv[4] = -INFINITY; ti[4] = INT_MAX;
    }
  }
  const double* g = gum + (size_t)t * 320 + b * 5;
  double bestv = mv[0] + g[0]; int best = 0;
#pragma unroll
  for (int k2 = 1; k2 < 5; ++k2) { double vv = mv[k2] + g[k2]; if (vv > bestv) { bestv = vv; best = k2; } }
  int nxt = mi[best];
  if (lane == 0) {
    out[b * TSZ + t] = (float)nxt;
    double m = mv[0];
    double ex[5]; double s = 0.0;
#pragma unroll
    for (int k2 = 0; k2 < 5; ++k2) { ex[k2] = exp(mv[k2] - m); s += ex[k2]; }
    float* po = out + BSZ * TSZ + ((size_t)b * TSZ + t) * 5;
#pragma unroll
    for (int k2 = 0; k2 < 5; ++k2) po[k2] = (float)(ex[k2] / s);
  }
  for (int k = lane; k < ESZ; k += 64)
    xt0[(size_t)k * 64 + b] = (double)embed[(size_t)nxt * ESZ + k];
}

// -------- initial embedding of SOS --------
__global__ __launch_bounds__(256) void k_emb0(const float* __restrict__ embed, const int* __restrict__ sos,
                                              double* __restrict__ xt0) {
  int idx = blockIdx.x * 256 + threadIdx.x;
  int b = idx & 63, k = idx >> 6;
  xt0[(size_t)k * 64 + b] = (double)embed[(size_t)sos[0] * ESZ + k];
}

extern "C" void kernel_launch(void* const* d_in, const int* in_sizes, int n_in,
                              void* d_out, int out_size, void* d_ws, size_t ws_size,
                              hipStream_t stream) {
  const float* hours = (const float*)d_in[0];
  const float* tp_w1 = (const float*)d_in[1];
  const float* tp_b1 = (const float*)d_in[2];
  const float* tp_w2 = (const float*)d_in[3];
  const float* tp_b2 = (const float*)d_in[4];
  const float* embed = (const float*)d_in[5];
  const float* w_ih0 = (const float*)d_in[6];
  const float* w_hh0 = (const float*)d_in[7];
  const float* b0    = (const float*)d_in[8];
  const float* w_ih1 = (const float*)d_in[9];
  const float* w_hh1 = (const float*)d_in[10];
  const float* b1    = (const float*)d_in[11];
  const float* fc_w  = (const float*)d_in[12];
  const float* fc_b  = (const float*)d_in[13];
  const int*   sos   = (const int*)d_in[14];
  float* out = (float*)d_out;

  char* w = (char*)d_ws;
  double* part = (double*)w;  w += (size_t)NSLOT * 64 * GC * 8;   // 54.5 MB split-K partials
  double* xt0  = (double*)w;  w += (size_t)ESZ * 64 * 8;
  double* h0T  = (double*)w;  w += (size_t)HSZ * 64 * 8;
  double* h1T  = (double*)w;  w += (size_t)HSZ * 64 * 8;
  double* c0   = (double*)w;  w += (size_t)BSZ * HSZ * 8;
  double* c1   = (double*)w;  w += (size_t)BSZ * HSZ * 8;
  double* tp1T = (double*)w;  w += (size_t)HSZ * 64 * 8;
  double* gum  = (double*)w;  w += (size_t)TSZ * 320 * 8;
  double* candV = (double*)w; w += (size_t)BSZ * NCAND * 8;       // 2.01 MB, b-major
  int*    candI = (int*)w;    w += (size_t)BSZ * NCAND * 4;       // 1.01 MB

  k_rng<<<dim3(100), dim3(256), 0, stream>>>(gum);
  k_time1<<<dim3(256), dim3(256), 0, stream>>>(hours, tp_w1, tp_b1, tp1T);
  k_gemm_simple<<<dim3(16, 8), dim3(256), 0, stream>>>(tp1T, tp_w2, 1024, 8, part);
  k_t2r<<<dim3(16, 64), dim3(256), 0, stream>>>(part, tp_b2, h0T, c0, h1T, c1);
  k_emb0<<<dim3(64), dim3(256), 0, stream>>>(embed, sos, xt0);

  double* part18 = part + (size_t)18 * 64 * GC;
  for (int t = 0; t < TSZ; ++t) {
    // A: slices 0-1 = xt0*w_ih0, 2-9 = h0*w_hh0, 10-17 = h1*w_hh1
    k_lstm<<<dim3(64, 18), dim3(256), 0, stream>>>(xt0, w_ih0, h0T, w_hh0, h1T, w_hh1, 2, 10, part);
    k_cell<<<dim3(4, 64), dim3(256), 0, stream>>>(part, 0, 10, b0, c0, h0T);
    // B: slices 0-7 = h0n*w_ih1 -> slots 18-25
    k_lstm<<<dim3(64, 8), dim3(256), 0, stream>>>(h0T, w_ih1, h0T, w_ih1, h0T, w_ih1, 8, 8, part18);
    k_cell<<<dim3(4, 64), dim3(256), 0, stream>>>(part, 10, 16, b1, c1, h1T);
    k_fctop<<<dim3(NFCB), dim3(256), 0, stream>>>(h1T, fc_w, fc_b, candV, candI);
    k_fin<<<dim3(64), dim3(64), 0, stream>>>(candV, candI, gum, t, embed, out, xt0);
  }
}

// Round 4
// 33759.302 us; speedup vs baseline: 1.7124x; 1.3208x over previous
//
#include <hip/hip_runtime.h>
#include <math.h>
#include <stdint.h>
#include <limits.h>

#define VSZ 50257
#define ESZ 256
#define HSZ 1024
#define BSZ 64
#define TSZ 80
#define GC  4096            // 4*H gate columns
#define NFCB 786            // ceil(VSZ/64) FC col-blocks
#define NCAND (NFCB*5)      // 3930 candidates per batch row
#define NSLOT 26            // part slots: A uses 0..17, B uses 18..25

typedef unsigned int u32;

// ---------------- Threefry-2x32 (JAX exact) ----------------
__device__ __forceinline__ void tf2x32(u32 k0, u32 k1, u32& x0, u32& x1) {
  u32 ks2 = k0 ^ k1 ^ 0x1BD11BDAu;
  x0 += k0; x1 += k1;
#define RND(r) { x0 += x1; x1 = (x1 << r) | (x1 >> (32 - r)); x1 ^= x0; }
  RND(13) RND(15) RND(26) RND(6)
  x0 += k1; x1 += ks2 + 1u;
  RND(17) RND(29) RND(16) RND(24)
  x0 += ks2; x1 += k0 + 2u;
  RND(13) RND(15) RND(26) RND(6)
  x0 += k0; x1 += k1 + 3u;
  RND(17) RND(29) RND(16) RND(24)
  x0 += k1; x1 += ks2 + 4u;
  RND(13) RND(15) RND(26) RND(6)
  x0 += ks2; x1 += k0 + 5u;
#undef RND
}

__device__ __forceinline__ double dsig(double x) { return 0.5 + 0.5 * tanh(0.5 * x); }

// sorted-desc top5 insert; ties -> lower index first (matches lax.top_k)
__device__ __forceinline__ void ins5(double v, int i, double* tv, int* ti) {
  bool beat4 = (v > tv[4]) || (v == tv[4] && i < ti[4]);
  if (!beat4) return;
  tv[4] = v; ti[4] = i;
#pragma unroll
  for (int p = 4; p > 0; --p) {
    bool sw = (tv[p] > tv[p-1]) || (tv[p] == tv[p-1] && ti[p] < ti[p-1]);
    double a0 = sw ? tv[p] : tv[p-1]; double a1 = sw ? tv[p-1] : tv[p];
    tv[p-1] = a0; tv[p] = a1;
    int b0 = sw ? ti[p] : ti[p-1]; int b1 = sw ? ti[p-1] : ti[p];
    ti[p-1] = b0; ti[p] = b1;
  }
}

// -------- fused RNG: gumbel[t][m] for t<80, m<320 --------
__global__ __launch_bounds__(256) void k_rng(double* __restrict__ gum) {
  int idx = blockIdx.x * 256 + threadIdx.x;
  if (idx >= TSZ * 320) return;
  int t = idx / 320, m = idx % 320;
  u32 a0 = 0u, a1 = (u32)t;
  tf2x32(0u, 42u, a0, a1);
  u32 x0 = 0u, x1 = (u32)m;
  tf2x32(a0, a1, x0, x1);
  u32 bits = x0 ^ x1;
  const float TINY = 1.17549435082228750797e-38f;  // 2^-126
  float f = __uint_as_float((bits >> 9) | 0x3f800000u) - 1.0f;
  float u = f + TINY;
  u = fmaxf(TINY, u);
  gum[idx] = -log(-log((double)u));
}

// -------- time encode stage 1 --------
__global__ __launch_bounds__(256) void k_time1(const float* __restrict__ hours, const float* __restrict__ w1,
                                               const float* __restrict__ bb1, double* __restrict__ tp1T) {
  int idx = blockIdx.x * 256 + threadIdx.x;  // 64*1024
  int b = idx & 63, hcol = idx >> 6;
  const float TPO = (float)(2.0 * 3.14159265358979323846 / 24.0);
  float af = hours[b] * TPO;
  double a = (double)af;
  double sv = sin(a), cv = cos(a);
  double vv = tanh(sv * (double)w1[hcol] + cv * (double)w1[HSZ + hcol] + (double)bb1[hcol]);
  tp1T[(size_t)hcol * 64 + b] = vv;
}

// -------- simple split-K gemm (prologue-only, runs once) --------
__global__ __launch_bounds__(256) void k_gemm_simple(const double* __restrict__ XTa, const float* __restrict__ Wa,
                                                     int Ka, int Sa, double* __restrict__ part) {
  int j = blockIdx.x * 256 + threadIdx.x;
  if (j >= GC) return;
  int s = blockIdx.y;
  int kc = Ka / Sa, k0 = s * kc;
  double acc[BSZ];
#pragma unroll
  for (int b = 0; b < BSZ; ++b) acc[b] = 0.0;
  const float* wp = Wa + (size_t)k0 * GC + j;
  const double* xp = XTa + (size_t)k0 * 64;
  for (int k = 0; k < kc; ++k) {
    double wv = (double)wp[0]; wp += GC;
#pragma unroll
    for (int b = 0; b < BSZ; ++b) acc[b] = fma(wv, xp[b], acc[b]);
    xp += 64;
  }
  double* o = part + ((size_t)s * 64) * GC + j;
#pragma unroll
  for (int b = 0; b < BSZ; ++b) o[(size_t)b * GC] = acc[b];
}

// -------- time encode stage 2 reduce --------
__global__ __launch_bounds__(256) void k_t2r(const double* __restrict__ part, const float* __restrict__ b2,
                                             double* __restrict__ h0T, double* __restrict__ c0,
                                             double* __restrict__ h1T, double* __restrict__ c1) {
  int b = blockIdx.y;
  int j = blockIdx.x * 256 + threadIdx.x;
  double acc = (double)b2[j];
  for (int s = 0; s < 8; ++s) acc += part[((size_t)s * 64 + b) * GC + j];
  int l = j >> 11, half = (j >> 10) & 1, hcol = j & 1023;
  if (half == 0) (l ? h1T : h0T)[(size_t)hcol * 64 + b] = acc;
  else           (l ? c1 : c0)[(size_t)b * HSZ + hcol] = acc;
}

#define FMABLK(W0V, W1V, KIDX)                                                        \
  {                                                                                   \
    double w0 = (double)(W0V), w1 = (double)(W1V);                                    \
    const double2* xp = (const double2*)xs + ((KIDX) << 5) + (bg << 2);               \
    double2 xa = xp[0], xb = xp[1], xc = xp[2], xd = xp[3];                           \
    acc[0][0] = fma(w0, xa.x, acc[0][0]); acc[0][1] = fma(w0, xa.y, acc[0][1]);       \
    acc[0][2] = fma(w0, xb.x, acc[0][2]); acc[0][3] = fma(w0, xb.y, acc[0][3]);       \
    acc[0][4] = fma(w0, xc.x, acc[0][4]); acc[0][5] = fma(w0, xc.y, acc[0][5]);       \
    acc[0][6] = fma(w0, xd.x, acc[0][6]); acc[0][7] = fma(w0, xd.y, acc[0][7]);       \
    acc[1][0] = fma(w1, xa.x, acc[1][0]); acc[1][1] = fma(w1, xa.y, acc[1][1]);       \
    acc[1][2] = fma(w1, xb.x, acc[1][2]); acc[1][3] = fma(w1, xb.y, acc[1][3]);       \
    acc[1][4] = fma(w1, xc.x, acc[1][4]); acc[1][5] = fma(w1, xc.y, acc[1][5]);       \
    acc[1][6] = fma(w1, xd.x, acc[1][6]); acc[1][7] = fma(w1, xd.y, acc[1][7]);       \
  }

// -------- LSTM gemm: 64-col blocks, 32KB LDS x-chunks, 8-deep weight prefetch --------
// grid (64, S). slice s: s<s1 -> (x0,W0,k0=s*128); s<s2 -> (x1,W1,(s-s1)*128); else (x2,W2,(s-s2)*128)
__global__ __launch_bounds__(256, 4) void k_lstm(const double* __restrict__ x0, const float* __restrict__ W0,
                                                 const double* __restrict__ x1, const float* __restrict__ W1,
                                                 const double* __restrict__ x2, const float* __restrict__ W2,
                                                 int s1, int s2, double* __restrict__ part) {
  __shared__ double xs[64 * 64];   // 32KB
  int tid = threadIdx.x;
  int vg = tid & 31, bg = tid >> 5;
  int colbase = blockIdx.x * 64;
  int s = blockIdx.y;
  const double* XT; const float* W; int k0;
  if (s < s1)      { XT = x0; W = W0; k0 = s * 128; }
  else if (s < s2) { XT = x1; W = W1; k0 = (s - s1) * 128; }
  else             { XT = x2; W = W2; k0 = (s - s2) * 128; }
  double acc[2][8];
#pragma unroll
  for (int i = 0; i < 2; ++i)
#pragma unroll
    for (int j = 0; j < 8; ++j) acc[i][j] = 0.0;
  float w0b[8], w1b[8];

  for (int ch = 0; ch < 2; ++ch) {
    const float* wr = W + (size_t)(k0 + ch * 64) * GC + colbase + vg;
    // chunk prologue: preload rows 0..7 (in flight across barrier + staging)
#pragma unroll
    for (int u = 0; u < 8; ++u) { w0b[u] = wr[0]; w1b[u] = wr[32]; wr += GC; }
    __syncthreads();
    const double2* src = (const double2*)(XT + (size_t)(k0 + ch * 64) * 64);
    double2* dst = (double2*)xs;
    for (int i = tid; i < 2048; i += 256) dst[i] = src[i];
    __syncthreads();
    // k = 0..55 with k+8 prefetch, 56..63 drain
    for (int kk = 0; kk < 56; kk += 8) {
#pragma unroll
      for (int u = 0; u < 8; ++u) {
        float nw0 = wr[0], nw1 = wr[32]; wr += GC;
        FMABLK(w0b[u], w1b[u], kk + u)
        w0b[u] = nw0; w1b[u] = nw1;
      }
    }
#pragma unroll
    for (int u = 0; u < 8; ++u) {
      FMABLK(w0b[u], w1b[u], 56 + u)
    }
  }
#pragma unroll
  for (int j = 0; j < 8; ++j) {
    int b = bg * 8 + j;
    double* o = part + ((size_t)s * 64 + b) * GC + colbase + vg;
    o[0]  = acc[0][j];
    o[32] = acc[1][j];
  }
}

// -------- LSTM cell: sum partial slots [sBeg, sBeg+S) + bias; gates i,f,g,o --------
__global__ __launch_bounds__(256) void k_cell(const double* __restrict__ part, int sBeg, int S,
                                              const float* __restrict__ bias,
                                              double* __restrict__ c, double* __restrict__ hT) {
  int b = blockIdx.y;
  int hcol = blockIdx.x * 256 + threadIdx.x;
  double gi = (double)bias[hcol];
  double gf = (double)bias[1024 + hcol];
  double gg = (double)bias[2048 + hcol];
  double go = (double)bias[3072 + hcol];
#pragma unroll 4
  for (int s = sBeg; s < sBeg + S; ++s) {
    const double* p = part + ((size_t)s * 64 + b) * GC;
    gi += p[hcol]; gf += p[1024 + hcol]; gg += p[2048 + hcol]; go += p[3072 + hcol];
  }
  size_t ci = (size_t)b * HSZ + hcol;
  double cn = dsig(gf) * c[ci] + dsig(gi) * tanh(gg);
  double hn = dsig(go) * tanh(cn);
  c[ci] = cn;
  hT[(size_t)hcol * 64 + b] = hn;
}

// -------- fused FC + per-block top5: 64 vocab cols/block, K=1024, 8-deep prefetch --------
__global__ __launch_bounds__(256, 4) void k_fctop(const double* __restrict__ h1T, const float* __restrict__ W,
                                                  const float* __restrict__ fcb,
                                                  double* __restrict__ candV, int* __restrict__ candI) {
  __shared__ double xs[64 * 64];   // 32KB: x-chunk staging, then 64b x 64v transpose buffer
  int tid = threadIdx.x;
  int vg = tid & 31, bg = tid >> 5;
  int vbase = blockIdx.x * 64;
  int c0 = min(vbase + vg,      VSZ - 1);
  int c1 = min(vbase + vg + 32, VSZ - 1);
  double acc[2][8];
#pragma unroll
  for (int i = 0; i < 2; ++i)
#pragma unroll
    for (int j = 0; j < 8; ++j) acc[i][j] = 0.0;
  float w0b[8], w1b[8];

  for (int ch = 0; ch < 16; ++ch) {
    const float* wr = W + (size_t)(ch * 64) * VSZ;
    // chunk prologue: preload rows 0..7 (overlaps barrier + x-staging)
#pragma unroll
    for (int u = 0; u < 8; ++u) { w0b[u] = wr[c0]; w1b[u] = wr[c1]; wr += VSZ; }
    __syncthreads();
    const double2* src = (const double2*)(h1T + (size_t)ch * 64 * 64);
    double2* dst = (double2*)xs;
    for (int i = tid; i < 2048; i += 256) dst[i] = src[i];
    __syncthreads();
    for (int kk = 0; kk < 56; kk += 8) {
#pragma unroll
      for (int u = 0; u < 8; ++u) {
        float nw0 = wr[c0], nw1 = wr[c1]; wr += VSZ;
        FMABLK(w0b[u], w1b[u], kk + u)
        w0b[u] = nw0; w1b[u] = nw1;
      }
    }
#pragma unroll
    for (int u = 0; u < 8; ++u) {
      FMABLK(w0b[u], w1b[u], 56 + u)
    }
  }
  __syncthreads();
  // bias + /TEMP, transpose into xs[b][(vl+b)&63] (swizzled, conflict-free)
#pragma unroll
  for (int i = 0; i < 2; ++i) {
    int v = vbase + vg + 32 * i;
    bool ok = (v < VSZ);
    double bi = ok ? (double)fcb[v] : 0.0;
    int vl = vg + 32 * i;
#pragma unroll
    for (int j = 0; j < 8; ++j) {
      int b = bg * 8 + j;
      double val = ok ? (acc[i][j] + bi) / 0.75 : -INFINITY;
      xs[b * 64 + ((vl + b) & 63)] = val;
    }
  }
  __syncthreads();
  if (tid < 64) {
    int b = tid;
    double tv[5]; int ti[5];
#pragma unroll
    for (int p = 0; p < 5; ++p) { tv[p] = -INFINITY; ti[p] = INT_MAX; }
    for (int vl = 0; vl < 64; ++vl)
      ins5(xs[b * 64 + ((vl + b) & 63)], vbase + vl, tv, ti);
#pragma unroll
    for (int r = 0; r < 5; ++r) {
      candV[(size_t)b * NCAND + blockIdx.x * 5 + r] = tv[r];
      candI[(size_t)b * NCAND + blockIdx.x * 5 + r] = ti[r];
    }
  }
}

// -------- final merge (3930 cands, b-major/coalesced) + gumbel sample + outputs --------
__global__ __launch_bounds__(64) void k_fin(const double* __restrict__ candV, const int* __restrict__ candI,
                                            const double* __restrict__ gum, int t,
                                            const float* __restrict__ embed,
                                            float* __restrict__ out, double* __restrict__ xt0) {
  int b = blockIdx.x, lane = threadIdx.x;
  double tv[5]; int ti[5];
#pragma unroll
  for (int p = 0; p < 5; ++p) { tv[p] = -INFINITY; ti[p] = INT_MAX; }
  const double* cv = candV + (size_t)b * NCAND;
  const int*    ci = candI + (size_t)b * NCAND;
  for (int e = lane; e < NCAND; e += 64)
    ins5(cv[e], ci[e], tv, ti);
  double mv[5]; int mi[5];
#pragma unroll
  for (int r = 0; r < 5; ++r) {
    double bv = tv[0]; int bi = ti[0];
    for (int off = 1; off < 64; off <<= 1) {
      double ov = __shfl_xor(bv, off, 64);
      int oi = __shfl_xor(bi, off, 64);
      if (ov > bv || (ov == bv && oi < bi)) { bv = ov; bi = oi; }
    }
    mv[r] = bv; mi[r] = bi;
    if (tv[0] == bv && ti[0] == bi) {
#pragma unroll
      for (int p = 0; p < 4; ++p) { tv[p] = tv[p+1]; ti[p] = ti[p+1]; }
      tv[4] = -INFINITY; ti[4] = INT_MAX;
    }
  }
  const double* g = gum + (size_t)t * 320 + b * 5;
  double bestv = mv[0] + g[0]; int best = 0;
#pragma unroll
  for (int k2 = 1; k2 < 5; ++k2) { double vv = mv[k2] + g[k2]; if (vv > bestv) { bestv = vv; best = k2; } }
  int nxt = mi[best];
  if (lane == 0) {
    out[b * TSZ + t] = (float)nxt;
    double m = mv[0];
    double ex[5]; double s = 0.0;
#pragma unroll
    for (int k2 = 0; k2 < 5; ++k2) { ex[k2] = exp(mv[k2] - m); s += ex[k2]; }
    float* po = out + BSZ * TSZ + ((size_t)b * TSZ + t) * 5;
#pragma unroll
    for (int k2 = 0; k2 < 5; ++k2) po[k2] = (float)(ex[k2] / s);
  }
  for (int k = lane; k < ESZ; k += 64)
    xt0[(size_t)k * 64 + b] = (double)embed[(size_t)nxt * ESZ + k];
}

// -------- initial embedding of SOS --------
__global__ __launch_bounds__(256) void k_emb0(const float* __restrict__ embed, const int* __restrict__ sos,
                                              double* __restrict__ xt0) {
  int idx = blockIdx.x * 256 + threadIdx.x;
  int b = idx & 63, k = idx >> 6;
  xt0[(size_t)k * 64 + b] = (double)embed[(size_t)sos[0] * ESZ + k];
}

extern "C" void kernel_launch(void* const* d_in, const int* in_sizes, int n_in,
                              void* d_out, int out_size, void* d_ws, size_t ws_size,
                              hipStream_t stream) {
  const float* hours = (const float*)d_in[0];
  const float* tp_w1 = (const float*)d_in[1];
  const float* tp_b1 = (const float*)d_in[2];
  const float* tp_w2 = (const float*)d_in[3];
  const float* tp_b2 = (const float*)d_in[4];
  const float* embed = (const float*)d_in[5];
  const float* w_ih0 = (const float*)d_in[6];
  const float* w_hh0 = (const float*)d_in[7];
  const float* b0    = (const float*)d_in[8];
  const float* w_ih1 = (const float*)d_in[9];
  const float* w_hh1 = (const float*)d_in[10];
  const float* b1    = (const float*)d_in[11];
  const float* fc_w  = (const float*)d_in[12];
  const float* fc_b  = (const float*)d_in[13];
  const int*   sos   = (const int*)d_in[14];
  float* out = (float*)d_out;

  char* w = (char*)d_ws;
  double* part = (double*)w;  w += (size_t)NSLOT * 64 * GC * 8;   // 54.5 MB split-K partials
  double* xt0  = (double*)w;  w += (size_t)ESZ * 64 * 8;
  double* h0T  = (double*)w;  w += (size_t)HSZ * 64 * 8;
  double* h1T  = (double*)w;  w += (size_t)HSZ * 64 * 8;
  double* c0   = (double*)w;  w += (size_t)BSZ * HSZ * 8;
  double* c1   = (double*)w;  w += (size_t)BSZ * HSZ * 8;
  double* tp1T = (double*)w;  w += (size_t)HSZ * 64 * 8;
  double* gum  = (double*)w;  w += (size_t)TSZ * 320 * 8;
  double* candV = (double*)w; w += (size_t)BSZ * NCAND * 8;       // 2.01 MB, b-major
  int*    candI = (int*)w;    w += (size_t)BSZ * NCAND * 4;       // 1.01 MB

  k_rng<<<dim3(100), dim3(256), 0, stream>>>(gum);
  k_time1<<<dim3(256), dim3(256), 0, stream>>>(hours, tp_w1, tp_b1, tp1T);
  k_gemm_simple<<<dim3(16, 8), dim3(256), 0, stream>>>(tp1T, tp_w2, 1024, 8, part);
  k_t2r<<<dim3(16, 64), dim3(256), 0, stream>>>(part, tp_b2, h0T, c0, h1T, c1);
  k_emb0<<<dim3(64), dim3(256), 0, stream>>>(embed, sos, xt0);

  double* part18 = part + (size_t)18 * 64 * GC;
  for (int t = 0; t < TSZ; ++t) {
    // A: slices 0-1 = xt0*w_ih0, 2-9 = h0*w_hh0, 10-17 = h1*w_hh1
    k_lstm<<<dim3(64, 18), dim3(256), 0, stream>>>(xt0, w_ih0, h0T, w_hh0, h1T, w_hh1, 2, 10, part);
    k_cell<<<dim3(4, 64), dim3(256), 0, stream>>>(part, 0, 10, b0, c0, h0T);
    // B: slices 0-7 = h0n*w_ih1 -> slots 18-25
    k_lstm<<<dim3(64, 8), dim3(256), 0, stream>>>(h0T, w_ih1, h0T, w_ih1, h0T, w_ih1, 8, 8, part18);
    k_cell<<<dim3(4, 64), dim3(256), 0, stream>>>(part, 10, 16, b1, c1, h1T);
    k_fctop<<<dim3(NFCB), dim3(256), 0, stream>>>(h1T, fc_w, fc_b, candV, candI);
    k_fin<<<dim3(64), dim3(64), 0, stream>>>(candV, candI, gum, t, embed, out, xt0);
  }
}